// Round 9
// baseline (351.701 us; speedup 1.0000x reference)
//
#include <hip/hip_runtime.h>
#include <math.h>

#define NTOK 8192
#define HD   2048
#define OD   1024
#define NE   8
#define CTXD 4096
#define CH   64

typedef short bf16x8 __attribute__((ext_vector_type(8)));
typedef float f32x4  __attribute__((ext_vector_type(4)));

static const size_t OFF_VN = (size_t)NTOK * OD;                 // v_next
static const size_t OFF_RP = 2 * (size_t)NTOK * OD;             // router_probs
static const size_t OFF_TI = OFF_RP + (size_t)NTOK * NE;        // top_k_idx
static const size_t OFF_TP = OFF_TI + (size_t)NTOK * 2;         // top_k_probs

// ---- ws byte offsets ----
#define WS_PCNT   0
#define WS_TOTAL  256
#define WS_TABLE  512
#define WS_PLIST  8192
#define WS_PWTS   (8192 + 64*NTOK*4)
#define WS_W1P    (WS_PWTS + 64*NTOK*8)
#define WS_W2P    (WS_W1P + NE*CTXD*CH*2)
#define WS_HID    (WS_W2P + NE*CH*3*OD*2)
#define WS_NEED   (WS_HID + 576*4096)

__device__ __forceinline__ unsigned bfpack2(float a, float b) {
    unsigned ua = __float_as_uint(a), ub = __float_as_uint(b);
    ua = (ua + 0x7FFFu + ((ua >> 16) & 1u)) >> 16;
    ub = (ub + 0x7FFFu + ((ub >> 16) & 1u)) >> 16;
    return ua | (ub << 16);
}
__device__ __forceinline__ float fsigmoid(float z) {
    return __fdividef(1.f, 1.f + __expf(-z));
}
__device__ __forceinline__ float fsoftplus(float z) {
    return fmaxf(z, 0.f) + __logf(1.f + __expf(-fabsf(z)));
}

// ---------------- fused pre-pass: convert W1 | convert W2 | router
__global__ __launch_bounds__(256) void pre_kernel(
    const float* __restrict__ h, const float* __restrict__ rw,
    const float* __restrict__ rb,
    const float* __restrict__ W1, const float* __restrict__ W2,
    unsigned short* __restrict__ W1p, unsigned short* __restrict__ W2p,
    float* __restrict__ out,
    int* __restrict__ pcnt, int* __restrict__ plist, float2* __restrict__ pwts)
{
    int bb = blockIdx.x;
    if (bb < 1024) {
        int flat = bb * 256 + threadIdx.x;
        int e = flat >> 15, rem = flat & 32767;
        int kb = rem >> 6, c = rem & 63;
        const float* src = W1 + (size_t)e * CTXD * CH + (size_t)kb * 8 * CH + c;
        uint4 o;
        o.x = bfpack2(src[0 * 64], src[1 * 64]);
        o.y = bfpack2(src[2 * 64], src[3 * 64]);
        o.z = bfpack2(src[4 * 64], src[5 * 64]);
        o.w = bfpack2(src[6 * 64], src[7 * 64]);
        *(uint4*)(W1p + (size_t)flat * 8) = o;
        return;
    }
    if (bb < 1792) {
        int flat = (bb - 1024) * 256 + threadIdx.x;
        int e = flat / 24576, rem = flat - e * 24576;
        int kb = rem / 3072, c = rem - kb * 3072;
        const float* src = W2 + ((size_t)e * CH + kb * 8) * (3 * OD) + c;
        uint4 o;
        o.x = bfpack2(src[0 * 3072], src[1 * 3072]);
        o.y = bfpack2(src[2 * 3072], src[3 * 3072]);
        o.z = bfpack2(src[4 * 3072], src[5 * 3072]);
        o.w = bfpack2(src[6 * 3072], src[7 * 3072]);
        *(uint4*)(W2p + (size_t)flat * 8) = o;
        return;
    }
    // ---- router ----
    int lane = threadIdx.x & 63;
    int wv   = threadIdx.x >> 6;
    int b    = (bb - 1792) * 4 + wv;
    const float4* h4 = (const float4*)(h + (size_t)b * HD);

    float a0=0.f,a1=0.f,a2=0.f,a3=0.f,a4=0.f,a5=0.f,a6=0.f,a7=0.f;
    #pragma unroll
    for (int i = 0; i < 8; i++) {
        int k4 = i * 64 + lane;
        float4 hv = h4[k4];
        const float4* wr = (const float4*)rw + (size_t)k4 * 8;
        float4 w00 = wr[0], w01 = wr[1];
        float4 w10 = wr[2], w11 = wr[3];
        float4 w20 = wr[4], w21 = wr[5];
        float4 w30 = wr[6], w31 = wr[7];
        a0 = fmaf(hv.x,w00.x,fmaf(hv.y,w10.x,fmaf(hv.z,w20.x,fmaf(hv.w,w30.x,a0))));
        a1 = fmaf(hv.x,w00.y,fmaf(hv.y,w10.y,fmaf(hv.z,w20.y,fmaf(hv.w,w30.y,a1))));
        a2 = fmaf(hv.x,w00.z,fmaf(hv.y,w10.z,fmaf(hv.z,w20.z,fmaf(hv.w,w30.z,a2))));
        a3 = fmaf(hv.x,w00.w,fmaf(hv.y,w10.w,fmaf(hv.z,w20.w,fmaf(hv.w,w30.w,a3))));
        a4 = fmaf(hv.x,w01.x,fmaf(hv.y,w11.x,fmaf(hv.z,w21.x,fmaf(hv.w,w31.x,a4))));
        a5 = fmaf(hv.x,w01.y,fmaf(hv.y,w11.y,fmaf(hv.z,w21.y,fmaf(hv.w,w31.y,a5))));
        a6 = fmaf(hv.x,w01.z,fmaf(hv.y,w11.z,fmaf(hv.z,w21.z,fmaf(hv.w,w31.z,a6))));
        a7 = fmaf(hv.x,w01.w,fmaf(hv.y,w11.w,fmaf(hv.z,w21.w,fmaf(hv.w,w31.w,a7))));
    }
    #pragma unroll
    for (int off = 32; off >= 1; off >>= 1) {
        a0 += __shfl_xor(a0, off); a1 += __shfl_xor(a1, off);
        a2 += __shfl_xor(a2, off); a3 += __shfl_xor(a3, off);
        a4 += __shfl_xor(a4, off); a5 += __shfl_xor(a5, off);
        a6 += __shfl_xor(a6, off); a7 += __shfl_xor(a7, off);
    }
    if (lane == 0) {
        float lg[8] = {a0+rb[0], a1+rb[1], a2+rb[2], a3+rb[3],
                       a4+rb[4], a5+rb[5], a6+rb[6], a7+rb[7]};
        float m = lg[0];
        #pragma unroll
        for (int e2 = 1; e2 < 8; e2++) m = fmaxf(m, lg[e2]);
        float p[8]; float s = 0.f;
        #pragma unroll
        for (int e2 = 0; e2 < 8; e2++) { p[e2] = expf(lg[e2] - m); s += p[e2]; }
        float inv = 1.f / s;
        #pragma unroll
        for (int e2 = 0; e2 < 8; e2++) {
            p[e2] *= inv;
            out[OFF_RP + (size_t)b * 8 + e2] = p[e2];
        }
        int e0 = 0;
        #pragma unroll
        for (int e2 = 1; e2 < 8; e2++) if (p[e2] > p[e0]) e0 = e2;
        int e1 = (e0 == 0) ? 1 : 0;
        #pragma unroll
        for (int e2 = 0; e2 < 8; e2++) {
            if (e2 == e0) continue;
            if (p[e2] > p[e1]) e1 = e2;
        }
        float s2 = p[e0] + p[e1];
        float w0 = p[e0] / s2, w1 = p[e1] / s2;
        out[OFF_TI + (size_t)b*2 + 0] = (float)e0;
        out[OFF_TI + (size_t)b*2 + 1] = (float)e1;
        out[OFF_TP + (size_t)b*2 + 0] = w0;
        out[OFF_TP + (size_t)b*2 + 1] = w1;
        int lo = min(e0, e1), hi = max(e0, e1);
        float wlo = (e0 < e1) ? w0 : w1;
        float whi = (e0 < e1) ? w1 : w0;
        int pid = lo * 8 + hi;
        int pos = atomicAdd(&pcnt[pid], 1);
        plist[pid * NTOK + pos] = b;
        pwts[pid * NTOK + pos] = make_float2(wlo, whi);
    }
}

// ---------------- prefix: pid counts -> dense 16-token tile table
__global__ void prefix_kernel(const int* __restrict__ pcnt,
                              int* __restrict__ table, int* __restrict__ total) {
    int tid = threadIdx.x;
    int cnt = pcnt[tid];
    int tiles = (cnt + 15) >> 4;
    int incl = tiles;
    #pragma unroll
    for (int off = 1; off < 64; off <<= 1) {
        int v = __shfl_up(incl, off);
        if (tid >= off) incl += v;
    }
    int base = incl - tiles;
    for (int i = 0; i < tiles; i++) table[base + i] = tid | (i << 6);
    if (tid == 63) *total = incl;
}

// ---------------- MoE template: V=0 full, V=1 stage1-only, V=2 stage2-only
template<int V>
__global__ __launch_bounds__(512) void moe_t(
    const float* __restrict__ h, const float* __restrict__ x,
    const float* __restrict__ v, const float* __restrict__ mu,
    const float* __restrict__ b1, const float* __restrict__ b2,
    const unsigned short* __restrict__ W1p, const unsigned short* __restrict__ W2p,
    const int* __restrict__ pcnt, const int* __restrict__ table,
    const int* __restrict__ total, const int* __restrict__ plist,
    const float2* __restrict__ pwts, unsigned* __restrict__ hid_g,
    float* __restrict__ out)
{
    __shared__ float part[16][64][8];            // 32 KB
    __shared__ unsigned short hid_s[16 * 128];   // 4 KB
    __shared__ int    toks[16];
    __shared__ float2 tw[16];

    int bid = (blockIdx.x & 7) * 72 + (blockIdx.x >> 3);   // XCD-chunked, 576=8*72
    if (bid >= *total) return;
    int entry = table[bid];
    int pid = entry & 63;
    int start = (entry >> 6) * 16;
    int lo = pid >> 3, hi = pid & 7;
    int cnt = pcnt[pid];
    int nt = cnt - start; if (nt > 16) nt = 16;

    int tid = threadIdx.x;
    if (tid < 16) {
        int idx = start + (tid < nt ? tid : 0);
        toks[tid] = plist[pid * NTOK + idx];
        tw[tid]   = pwts[pid * NTOK + idx];
    }
    __syncthreads();

    int lane = tid & 63, w = tid >> 6;           // 8 waves
    int l15 = lane & 15, lq = lane >> 4;

    if constexpr (V == 0 || V == 1) {
        // ---- stage 1: wave = (expert slot, K-quarter); 16 tok x 64 col
        int s1s = w >> 2;
        int kq  = w & 3;
        int myE = s1s ? hi : lo;
        const unsigned short* W1e = W1p + (size_t)myE * (CTXD * CH);

        int tokA = toks[l15];
        const float* base;
        if (kq < 2)       base = h + (size_t)tokA * HD + kq * 1024;
        else if (kq == 2) base = x + (size_t)tokA * OD;
        else              base = v + (size_t)tokA * OD;

        f32x4 acc[4];
        #pragma unroll
        for (int cg = 0; cg < 4; cg++) acc[cg] = (f32x4){0.f,0.f,0.f,0.f};

        #pragma unroll 2
        for (int c = 0; c < 8; c++) {
            const float* cb = base + c * 128;
            bf16x8 a[4];
            #pragma unroll
            for (int ks = 0; ks < 4; ks++) {
                const float4* s = (const float4*)(cb + ks * 32 + lq * 8);
                float4 f0 = s[0], f1 = s[1];
                uint4 pk;
                pk.x = bfpack2(f0.x, f0.y);
                pk.y = bfpack2(f0.z, f0.w);
                pk.z = bfpack2(f1.x, f1.y);
                pk.w = bfpack2(f1.z, f1.w);
                a[ks] = __builtin_bit_cast(bf16x8, pk);
            }
            #pragma unroll
            for (int ks = 0; ks < 4; ks++) {
                int kb = kq * 128 + c * 16 + ks * 4 + lq;
                const unsigned short* wp = W1e + (size_t)kb * 512;
                #pragma unroll
                for (int cg = 0; cg < 4; cg++) {
                    bf16x8 bfr = *(const bf16x8*)(wp + (size_t)(cg * 16 + l15) * 8);
                    acc[cg] = __builtin_amdgcn_mfma_f32_16x16x32_bf16(a[ks], bfr, acc[cg], 0, 0, 0);
                }
            }
        }

        #pragma unroll
        for (int cg = 0; cg < 4; cg++)
            #pragma unroll
            for (int i = 0; i < 4; i++)
                part[lq * 4 + i][cg * 16 + l15][s1s * 4 + kq] = acc[cg][i];
        __syncthreads();

        // reduce: 512 thr -> 2048 hid values
        {
            int rs   = tid >> 8;
            int rtok = (tid >> 4) & 15;
            int rc4  = (tid & 15) * 4;
            int eS = rs ? hi : lo;
            float sm[4];
            #pragma unroll
            for (int j = 0; j < 4; j++) {
                f32x4 p = *(const f32x4*)&part[rtok][rc4 + j][rs * 4];
                float sv = p[0] + p[1] + p[2] + p[3] + b1[eS * CH + rc4 + j];
                sm[j] = sv > 0.f ? sv : 0.f;
            }
            uint2 u = make_uint2(bfpack2(sm[0], sm[1]), bfpack2(sm[2], sm[3]));
            if constexpr (V == 1) {
                // stage1-only: persist hid tile to scratch and exit
                *(uint2*)(hid_g + (size_t)bid * 1024 + tid * 2) = u;
            } else {
                int byte = (rtok * 256 + (rs * 64 + rc4) * 2) ^ ((rtok & 7) << 4);
                *(uint2*)((char*)hid_s + byte) = u;
            }
        }
        if constexpr (V == 1) return;
        __syncthreads();
    }

    if constexpr (V == 2) {
        // stage2-only: load hid tile from scratch into swizzled LDS
        uint2 u = *(const uint2*)(hid_g + (size_t)bid * 1024 + tid * 2);
        int rtok = (tid >> 4) & 15;
        int rc4  = (tid & 15) * 4;
        int rs   = tid >> 8;
        int byte = (rtok * 256 + (rs * 64 + rc4) * 2) ^ ((rtok & 7) << 4);
        *(uint2*)((char*)hid_s + byte) = u;
        __syncthreads();
    }

    // ---- stage 2: wave w owns o-band [w*128, w*128+128)
    bf16x8 af[2][2];
    #pragma unroll
    for (int s = 0; s < 2; s++)
        #pragma unroll
        for (int ks = 0; ks < 2; ks++) {
            int col = s * 64 + ks * 32 + lq * 8;
            int by = (l15 * 256 + col * 2) ^ ((l15 & 7) << 4);
            af[s][ks] = *(const bf16x8*)((const char*)hid_s + by);
        }

    const unsigned short* W2lo = W2p + (size_t)lo * (CH * 3 * OD);
    const unsigned short* W2hi = W2p + (size_t)hi * (CH * 3 * OD);
    const float* b2lo = b2 + (size_t)lo * 3072;
    const float* b2hi = b2 + (size_t)hi * 3072;

    int   tok_r[4];
    float twx[4], twy[4];
    #pragma unroll
    for (int i = 0; i < 4; i++) {
        int trow = lq * 4 + i;
        tok_r[i] = toks[trow];
        float2 t2 = tw[trow];
        twx[i] = t2.x; twy[i] = t2.y;
    }

    for (int ot = 0; ot < 8; ot++) {
        int o = w * 128 + ot * 16 + l15;
        float xo[4], vo[4];
        #pragma unroll
        for (int i = 0; i < 4; i++) {
            size_t off = (size_t)tok_r[i] * OD + o;
            xo[i] = x[off];
            vo[i] = v[off];
        }
        float muo = mu[o];
        float accVN[4] = {0.f,0.f,0.f,0.f};
        float accGV[4] = {0.f,0.f,0.f,0.f};

        #pragma unroll
        for (int s = 0; s < 2; s++) {
            const unsigned short* W2e = s ? W2hi : W2lo;
            const float* b2e = s ? b2hi : b2lo;
            f32x4 aA = {0.f,0.f,0.f,0.f};
            f32x4 aB = {0.f,0.f,0.f,0.f};
            f32x4 aG = {0.f,0.f,0.f,0.f};
            #pragma unroll
            for (int ks = 0; ks < 2; ks++) {
                int kb = ks * 4 + lq;
                bf16x8 wA = *(const bf16x8*)(W2e + ((size_t)kb * 3072 + o) * 8);
                bf16x8 wB = *(const bf16x8*)(W2e + ((size_t)kb * 3072 + OD + o) * 8);
                bf16x8 wG = *(const bf16x8*)(W2e + ((size_t)kb * 3072 + 2 * OD + o) * 8);
                aA = __builtin_amdgcn_mfma_f32_16x16x32_bf16(af[s][ks], wA, aA, 0, 0, 0);
                aB = __builtin_amdgcn_mfma_f32_16x16x32_bf16(af[s][ks], wB, aB, 0, 0, 0);
                aG = __builtin_amdgcn_mfma_f32_16x16x32_bf16(af[s][ks], wG, aG, 0, 0, 0);
            }
            float ba = b2e[o], bb = b2e[OD + o], bg = b2e[2 * OD + o];
            #pragma unroll
            for (int i = 0; i < 4; i++) {
                float za = aA[i] + ba;
                float zb = aB[i] + bb;
                float zg = aG[i] + bg;
                float alpha = fsigmoid(za);
                float beta  = fsoftplus(zb);
                float gate  = fsigmoid(zg);
                float ws = s ? twy[i] : twx[i];
                float vn_s = alpha * vo[i] - beta * (xo[i] - muo);
                accVN[i] += ws * vn_s;
                accGV[i] += ws * gate * vn_s;
            }
        }
        #pragma unroll
        for (int i = 0; i < 4; i++) {
            if (lq * 4 + i < nt) {
                size_t off = (size_t)tok_r[i] * OD + o;
                out[off]          = xo[i] + 0.1f * accGV[i];
                out[OFF_VN + off] = accVN[i];
            }
        }
    }
}

extern "C" void kernel_launch(void* const* d_in, const int* in_sizes, int n_in,
                              void* d_out, int out_size, void* d_ws, size_t ws_size,
                              hipStream_t stream)
{
    (void)in_sizes; (void)n_in; (void)out_size;
    const float* h  = (const float*)d_in[0];
    const float* x  = (const float*)d_in[1];
    const float* v  = (const float*)d_in[2];
    const float* rw = (const float*)d_in[3];
    const float* rb = (const float*)d_in[4];
    const float* mu = (const float*)d_in[5];
    const float* W1 = (const float*)d_in[6];
    const float* b1 = (const float*)d_in[7];
    const float* W2 = (const float*)d_in[8];
    const float* b2 = (const float*)d_in[9];
    float* out = (float*)d_out;

    char* ws = (char*)d_ws;
    int*    pcnt  = (int*)(ws + WS_PCNT);
    int*    total = (int*)(ws + WS_TOTAL);
    int*    table = (int*)(ws + WS_TABLE);
    int*    plist = (int*)(ws + WS_PLIST);
    float2* pwts  = (float2*)(ws + WS_PWTS);
    unsigned short* W1p = (unsigned short*)(ws + WS_W1P);
    unsigned short* W2p = (unsigned short*)(ws + WS_W2P);
    unsigned* hid_g = (unsigned*)(ws + WS_HID);

    hipMemsetAsync(pcnt, 0, 64 * sizeof(int), stream);

    pre_kernel<<<3840, 256, 0, stream>>>(h, rw, rb, W1, W2, W1p, W2p,
                                         out, pcnt, plist, pwts);
    prefix_kernel<<<1, 64, 0, stream>>>(pcnt, table, total);

    // Ablation dispatches (only if ws has room for the hid scratch).
    // s2 writes real out cells; moe_t<0> rewrites every one of them after.
    if (ws_size >= (size_t)WS_NEED) {
        moe_t<1><<<576, 512, 0, stream>>>(h, x, v, mu, b1, b2, W1p, W2p,
                                          pcnt, table, total, plist, pwts, hid_g, out);
        moe_t<2><<<576, 512, 0, stream>>>(h, x, v, mu, b1, b2, W1p, W2p,
                                          pcnt, table, total, plist, pwts, hid_g, out);
    }
    moe_t<0><<<576, 512, 0, stream>>>(h, x, v, mu, b1, b2, W1p, W2p,
                                      pcnt, table, total, plist, pwts, hid_g, out);
}

// Round 10
// 229.414 us; speedup vs baseline: 1.5330x; 1.5330x over previous
//
#include <hip/hip_runtime.h>
#include <math.h>

#define NTOK 8192
#define HD   2048
#define OD   1024
#define NE   8
#define CTXD 4096
#define CH   64

typedef short bf16x8 __attribute__((ext_vector_type(8)));
typedef float f32x4  __attribute__((ext_vector_type(4)));

static const size_t OFF_VN = (size_t)NTOK * OD;                 // v_next
static const size_t OFF_RP = 2 * (size_t)NTOK * OD;             // router_probs
static const size_t OFF_TI = OFF_RP + (size_t)NTOK * NE;        // top_k_idx
static const size_t OFF_TP = OFF_TI + (size_t)NTOK * 2;         // top_k_probs

// ---- ws byte offsets ----
#define WS_PCNT   0
#define WS_TOTAL  256
#define WS_TABLE  512
#define WS_PLIST  8192
#define WS_PWTS   (8192 + 64*NTOK*4)
#define WS_W1P    (WS_PWTS + 64*NTOK*8)
#define WS_W2P    (WS_W1P + NE*CTXD*CH*2)
#define WS_CTXB   (WS_W2P + NE*CH*3*OD*2)
#define WS_NEED2  ((size_t)WS_CTXB + (size_t)NTOK*CTXD*2)   // + 64 MB ctx bf16

__device__ __forceinline__ unsigned bfpack2(float a, float b) {
    unsigned ua = __float_as_uint(a), ub = __float_as_uint(b);
    ua = (ua + 0x7FFFu + ((ua >> 16) & 1u)) >> 16;
    ub = (ub + 0x7FFFu + ((ub >> 16) & 1u)) >> 16;
    return ua | (ub << 16);
}
__device__ __forceinline__ float fsigmoid(float z) {
    return __fdividef(1.f, 1.f + __expf(-z));
}
__device__ __forceinline__ float fsoftplus(float z) {
    return fmaxf(z, 0.f) + __logf(1.f + __expf(-fabsf(z)));
}

// ---------------- fused pre-pass: convert W1 | convert W2 | router | ctx->bf16
// blocks [0,1024): W1 -> W1p [8][512][64][8]
// blocks [1024,1792): W2 -> W2p [8][8][3072][8]
// blocks [1792,3840): router (4 tok/block)
// blocks [3840,12032): ctx bf16 conversion (1 token row/block) -- only if launched
__global__ __launch_bounds__(256) void pre_kernel(
    const float* __restrict__ h, const float* __restrict__ x,
    const float* __restrict__ v, const float* __restrict__ rw,
    const float* __restrict__ rb,
    const float* __restrict__ W1, const float* __restrict__ W2,
    unsigned short* __restrict__ W1p, unsigned short* __restrict__ W2p,
    unsigned short* __restrict__ ctxb,
    float* __restrict__ out,
    int* __restrict__ pcnt, int* __restrict__ plist, float2* __restrict__ pwts)
{
    int bb = blockIdx.x;
    if (bb < 1024) {
        int flat = bb * 256 + threadIdx.x;
        int e = flat >> 15, rem = flat & 32767;
        int kb = rem >> 6, c = rem & 63;
        const float* src = W1 + (size_t)e * CTXD * CH + (size_t)kb * 8 * CH + c;
        uint4 o;
        o.x = bfpack2(src[0 * 64], src[1 * 64]);
        o.y = bfpack2(src[2 * 64], src[3 * 64]);
        o.z = bfpack2(src[4 * 64], src[5 * 64]);
        o.w = bfpack2(src[6 * 64], src[7 * 64]);
        *(uint4*)(W1p + (size_t)flat * 8) = o;
        return;
    }
    if (bb < 1792) {
        int flat = (bb - 1024) * 256 + threadIdx.x;
        int e = flat / 24576, rem = flat - e * 24576;
        int kb = rem / 3072, c = rem - kb * 3072;
        const float* src = W2 + ((size_t)e * CH + kb * 8) * (3 * OD) + c;
        uint4 o;
        o.x = bfpack2(src[0 * 3072], src[1 * 3072]);
        o.y = bfpack2(src[2 * 3072], src[3 * 3072]);
        o.z = bfpack2(src[4 * 3072], src[5 * 3072]);
        o.w = bfpack2(src[6 * 3072], src[7 * 3072]);
        *(uint4*)(W2p + (size_t)flat * 8) = o;
        return;
    }
    if (bb >= 3840) {
        // ---- ctx -> bf16: one token row per block; thread tid does 16 elems
        int t = bb - 3840;
        int col = threadIdx.x * 16;
        const float* src;
        if (col < HD)           src = h + (size_t)t * HD + col;
        else if (col < HD + OD) src = x + (size_t)t * OD + (col - HD);
        else                    src = v + (size_t)t * OD + (col - HD - OD);
        float4 f0 = ((const float4*)src)[0];
        float4 f1 = ((const float4*)src)[1];
        float4 f2 = ((const float4*)src)[2];
        float4 f3 = ((const float4*)src)[3];
        uint4 o0, o1;
        o0.x = bfpack2(f0.x, f0.y); o0.y = bfpack2(f0.z, f0.w);
        o0.z = bfpack2(f1.x, f1.y); o0.w = bfpack2(f1.z, f1.w);
        o1.x = bfpack2(f2.x, f2.y); o1.y = bfpack2(f2.z, f2.w);
        o1.z = bfpack2(f3.x, f3.y); o1.w = bfpack2(f3.z, f3.w);
        uint4* dst = (uint4*)(ctxb + (size_t)t * CTXD + col);
        dst[0] = o0; dst[1] = o1;
        return;
    }
    // ---- router ----
    int lane = threadIdx.x & 63;
    int wv   = threadIdx.x >> 6;
    int b    = (bb - 1792) * 4 + wv;
    const float4* h4 = (const float4*)(h + (size_t)b * HD);

    float a0=0.f,a1=0.f,a2=0.f,a3=0.f,a4=0.f,a5=0.f,a6=0.f,a7=0.f;
    #pragma unroll
    for (int i = 0; i < 8; i++) {
        int k4 = i * 64 + lane;
        float4 hv = h4[k4];
        const float4* wr = (const float4*)rw + (size_t)k4 * 8;
        float4 w00 = wr[0], w01 = wr[1];
        float4 w10 = wr[2], w11 = wr[3];
        float4 w20 = wr[4], w21 = wr[5];
        float4 w30 = wr[6], w31 = wr[7];
        a0 = fmaf(hv.x,w00.x,fmaf(hv.y,w10.x,fmaf(hv.z,w20.x,fmaf(hv.w,w30.x,a0))));
        a1 = fmaf(hv.x,w00.y,fmaf(hv.y,w10.y,fmaf(hv.z,w20.y,fmaf(hv.w,w30.y,a1))));
        a2 = fmaf(hv.x,w00.z,fmaf(hv.y,w10.z,fmaf(hv.z,w20.z,fmaf(hv.w,w30.z,a2))));
        a3 = fmaf(hv.x,w00.w,fmaf(hv.y,w10.w,fmaf(hv.z,w20.w,fmaf(hv.w,w30.w,a3))));
        a4 = fmaf(hv.x,w01.x,fmaf(hv.y,w11.x,fmaf(hv.z,w21.x,fmaf(hv.w,w31.x,a4))));
        a5 = fmaf(hv.x,w01.y,fmaf(hv.y,w11.y,fmaf(hv.z,w21.y,fmaf(hv.w,w31.y,a5))));
        a6 = fmaf(hv.x,w01.z,fmaf(hv.y,w11.z,fmaf(hv.z,w21.z,fmaf(hv.w,w31.z,a6))));
        a7 = fmaf(hv.x,w01.w,fmaf(hv.y,w11.w,fmaf(hv.z,w21.w,fmaf(hv.w,w31.w,a7))));
    }
    #pragma unroll
    for (int off = 32; off >= 1; off >>= 1) {
        a0 += __shfl_xor(a0, off); a1 += __shfl_xor(a1, off);
        a2 += __shfl_xor(a2, off); a3 += __shfl_xor(a3, off);
        a4 += __shfl_xor(a4, off); a5 += __shfl_xor(a5, off);
        a6 += __shfl_xor(a6, off); a7 += __shfl_xor(a7, off);
    }
    if (lane == 0) {
        float lg[8] = {a0+rb[0], a1+rb[1], a2+rb[2], a3+rb[3],
                       a4+rb[4], a5+rb[5], a6+rb[6], a7+rb[7]};
        float m = lg[0];
        #pragma unroll
        for (int e2 = 1; e2 < 8; e2++) m = fmaxf(m, lg[e2]);
        float p[8]; float s = 0.f;
        #pragma unroll
        for (int e2 = 0; e2 < 8; e2++) { p[e2] = expf(lg[e2] - m); s += p[e2]; }
        float inv = 1.f / s;
        #pragma unroll
        for (int e2 = 0; e2 < 8; e2++) {
            p[e2] *= inv;
            out[OFF_RP + (size_t)b * 8 + e2] = p[e2];
        }
        int e0 = 0;
        #pragma unroll
        for (int e2 = 1; e2 < 8; e2++) if (p[e2] > p[e0]) e0 = e2;
        int e1 = (e0 == 0) ? 1 : 0;
        #pragma unroll
        for (int e2 = 0; e2 < 8; e2++) {
            if (e2 == e0) continue;
            if (p[e2] > p[e1]) e1 = e2;
        }
        float s2 = p[e0] + p[e1];
        float w0 = p[e0] / s2, w1 = p[e1] / s2;
        out[OFF_TI + (size_t)b*2 + 0] = (float)e0;
        out[OFF_TI + (size_t)b*2 + 1] = (float)e1;
        out[OFF_TP + (size_t)b*2 + 0] = w0;
        out[OFF_TP + (size_t)b*2 + 1] = w1;
        int lo = min(e0, e1), hi = max(e0, e1);
        float wlo = (e0 < e1) ? w0 : w1;
        float whi = (e0 < e1) ? w1 : w0;
        int pid = lo * 8 + hi;
        int pos = atomicAdd(&pcnt[pid], 1);
        plist[pid * NTOK + pos] = b;
        pwts[pid * NTOK + pos] = make_float2(wlo, whi);
    }
}

// ---------------- prefix: pid counts -> dense 16-token tile table
__global__ void prefix_kernel(const int* __restrict__ pcnt,
                              int* __restrict__ table, int* __restrict__ total) {
    int tid = threadIdx.x;
    int cnt = pcnt[tid];
    int tiles = (cnt + 15) >> 4;
    int incl = tiles;
    #pragma unroll
    for (int off = 1; off < 64; off <<= 1) {
        int v = __shfl_up(incl, off);
        if (tid >= off) incl += v;
    }
    int base = incl - tiles;
    for (int i = 0; i < tiles; i++) table[base + i] = tid | (i << 6);
    if (tid == 63) *total = incl;
}

// ---------------- MoE: PRECONV=1 reads bf16 ctxb; PRECONV=0 packs in-loop
template<bool PRECONV>
__global__ __launch_bounds__(512) void moe_t(
    const float* __restrict__ h, const float* __restrict__ x,
    const float* __restrict__ v, const float* __restrict__ mu,
    const float* __restrict__ b1, const float* __restrict__ b2,
    const unsigned short* __restrict__ W1p, const unsigned short* __restrict__ W2p,
    const unsigned short* __restrict__ ctxb,
    const int* __restrict__ pcnt, const int* __restrict__ table,
    const int* __restrict__ total, const int* __restrict__ plist,
    const float2* __restrict__ pwts, float* __restrict__ out)
{
    __shared__ float part[16][64][8];            // 32 KB
    __shared__ unsigned short hid_s[16 * 128];   // 4 KB
    __shared__ int    toks[16];
    __shared__ float2 tw[16];

    int bid = (blockIdx.x & 7) * 72 + (blockIdx.x >> 3);   // XCD-chunked, 576=8*72
    if (bid >= *total) return;
    int entry = table[bid];
    int pid = entry & 63;
    int start = (entry >> 6) * 16;
    int lo = pid >> 3, hi = pid & 7;
    int cnt = pcnt[pid];
    int nt = cnt - start; if (nt > 16) nt = 16;

    int tid = threadIdx.x;
    if (tid < 16) {
        int idx = start + (tid < nt ? tid : 0);
        toks[tid] = plist[pid * NTOK + idx];
        tw[tid]   = pwts[pid * NTOK + idx];
    }
    __syncthreads();

    int lane = tid & 63, w = tid >> 6;           // 8 waves
    int l15 = lane & 15, lq = lane >> 4;

    // ---- stage 1: wave = (expert slot, K-quarter); 16 tok x 64 col
    {
        int s1s = w >> 2;
        int kq  = w & 3;
        int myE = s1s ? hi : lo;
        const unsigned short* W1e = W1p + (size_t)myE * (CTXD * CH);
        int tokA = toks[l15];

        f32x4 acc[4];
        #pragma unroll
        for (int cg = 0; cg < 4; cg++) acc[cg] = (f32x4){0.f,0.f,0.f,0.f};

        if constexpr (PRECONV) {
            const unsigned short* base = ctxb + (size_t)tokA * CTXD + kq * 1024;
            #pragma unroll 4
            for (int c = 0; c < 8; c++) {
                bf16x8 a[4];
                #pragma unroll
                for (int ks = 0; ks < 4; ks++)
                    a[ks] = *(const bf16x8*)(base + c * 128 + ks * 32 + lq * 8);
                #pragma unroll
                for (int ks = 0; ks < 4; ks++) {
                    int kb = kq * 128 + c * 16 + ks * 4 + lq;
                    const unsigned short* wp = W1e + (size_t)kb * 512;
                    #pragma unroll
                    for (int cg = 0; cg < 4; cg++) {
                        bf16x8 bfr = *(const bf16x8*)(wp + (size_t)(cg * 16 + l15) * 8);
                        acc[cg] = __builtin_amdgcn_mfma_f32_16x16x32_bf16(a[ks], bfr, acc[cg], 0, 0, 0);
                    }
                }
            }
        } else {
            const float* base;
            if (kq < 2)       base = h + (size_t)tokA * HD + kq * 1024;
            else if (kq == 2) base = x + (size_t)tokA * OD;
            else              base = v + (size_t)tokA * OD;
            #pragma unroll 2
            for (int c = 0; c < 8; c++) {
                const float* cb = base + c * 128;
                bf16x8 a[4];
                #pragma unroll
                for (int ks = 0; ks < 4; ks++) {
                    const float4* s = (const float4*)(cb + ks * 32 + lq * 8);
                    float4 f0 = s[0], f1 = s[1];
                    uint4 pk;
                    pk.x = bfpack2(f0.x, f0.y);
                    pk.y = bfpack2(f0.z, f0.w);
                    pk.z = bfpack2(f1.x, f1.y);
                    pk.w = bfpack2(f1.z, f1.w);
                    a[ks] = __builtin_bit_cast(bf16x8, pk);
                }
                #pragma unroll
                for (int ks = 0; ks < 4; ks++) {
                    int kb = kq * 128 + c * 16 + ks * 4 + lq;
                    const unsigned short* wp = W1e + (size_t)kb * 512;
                    #pragma unroll
                    for (int cg = 0; cg < 4; cg++) {
                        bf16x8 bfr = *(const bf16x8*)(wp + (size_t)(cg * 16 + l15) * 8);
                        acc[cg] = __builtin_amdgcn_mfma_f32_16x16x32_bf16(a[ks], bfr, acc[cg], 0, 0, 0);
                    }
                }
            }
        }

        #pragma unroll
        for (int cg = 0; cg < 4; cg++)
            #pragma unroll
            for (int i = 0; i < 4; i++)
                part[lq * 4 + i][cg * 16 + l15][s1s * 4 + kq] = acc[cg][i];
    }
    __syncthreads();

    // ---- reduce: 512 thr -> 2048 hid values (sum 4 kq + bias + relu -> bf16)
    {
        int rs   = tid >> 8;
        int rtok = (tid >> 4) & 15;
        int rc4  = (tid & 15) * 4;
        int eS = rs ? hi : lo;
        float sm[4];
        #pragma unroll
        for (int j = 0; j < 4; j++) {
            f32x4 p = *(const f32x4*)&part[rtok][rc4 + j][rs * 4];
            float sv = p[0] + p[1] + p[2] + p[3] + b1[eS * CH + rc4 + j];
            sm[j] = sv > 0.f ? sv : 0.f;
        }
        uint2 u = make_uint2(bfpack2(sm[0], sm[1]), bfpack2(sm[2], sm[3]));
        int byte = (rtok * 256 + (rs * 64 + rc4) * 2) ^ ((rtok & 7) << 4);
        *(uint2*)((char*)hid_s + byte) = u;
    }
    __syncthreads();

    // ---- stage 2: wave w owns o-band [w*128, w*128+128)
    bf16x8 af[2][2];
    #pragma unroll
    for (int s = 0; s < 2; s++)
        #pragma unroll
        for (int ks = 0; ks < 2; ks++) {
            int col = s * 64 + ks * 32 + lq * 8;
            int by = (l15 * 256 + col * 2) ^ ((l15 & 7) << 4);
            af[s][ks] = *(const bf16x8*)((const char*)hid_s + by);
        }

    const unsigned short* W2lo = W2p + (size_t)lo * (CH * 3 * OD);
    const unsigned short* W2hi = W2p + (size_t)hi * (CH * 3 * OD);
    const float* b2lo = b2 + (size_t)lo * 3072;
    const float* b2hi = b2 + (size_t)hi * 3072;

    int   tok_r[4];
    float twx[4], twy[4];
    #pragma unroll
    for (int i = 0; i < 4; i++) {
        int trow = lq * 4 + i;
        tok_r[i] = toks[trow];
        float2 t2 = tw[trow];
        twx[i] = t2.x; twy[i] = t2.y;
    }

    for (int ot = 0; ot < 8; ot++) {
        int o = w * 128 + ot * 16 + l15;
        float xo[4], vo[4];
        #pragma unroll
        for (int i = 0; i < 4; i++) {
            size_t off = (size_t)tok_r[i] * OD + o;
            xo[i] = x[off];
            vo[i] = v[off];
        }
        float muo = mu[o];
        float accVN[4] = {0.f,0.f,0.f,0.f};
        float accGV[4] = {0.f,0.f,0.f,0.f};

        #pragma unroll
        for (int s = 0; s < 2; s++) {
            const unsigned short* W2e = s ? W2hi : W2lo;
            const float* b2e = s ? b2hi : b2lo;
            f32x4 aA = {0.f,0.f,0.f,0.f};
            f32x4 aB = {0.f,0.f,0.f,0.f};
            f32x4 aG = {0.f,0.f,0.f,0.f};
            #pragma unroll
            for (int ks = 0; ks < 2; ks++) {
                int kb = ks * 4 + lq;
                bf16x8 wA = *(const bf16x8*)(W2e + ((size_t)kb * 3072 + o) * 8);
                bf16x8 wB = *(const bf16x8*)(W2e + ((size_t)kb * 3072 + OD + o) * 8);
                bf16x8 wG = *(const bf16x8*)(W2e + ((size_t)kb * 3072 + 2 * OD + o) * 8);
                aA = __builtin_amdgcn_mfma_f32_16x16x32_bf16(af[s][ks], wA, aA, 0, 0, 0);
                aB = __builtin_amdgcn_mfma_f32_16x16x32_bf16(af[s][ks], wB, aB, 0, 0, 0);
                aG = __builtin_amdgcn_mfma_f32_16x16x32_bf16(af[s][ks], wG, aG, 0, 0, 0);
            }
            float ba = b2e[o], bb = b2e[OD + o], bg = b2e[2 * OD + o];
            #pragma unroll
            for (int i = 0; i < 4; i++) {
                float za = aA[i] + ba;
                float zb = aB[i] + bb;
                float zg = aG[i] + bg;
                float alpha = fsigmoid(za);
                float beta  = fsoftplus(zb);
                float gate  = fsigmoid(zg);
                float ws = s ? twy[i] : twx[i];
                float vn_s = alpha * vo[i] - beta * (xo[i] - muo);
                accVN[i] += ws * vn_s;
                accGV[i] += ws * gate * vn_s;
            }
        }
        #pragma unroll
        for (int i = 0; i < 4; i++) {
            if (lq * 4 + i < nt) {
                size_t off = (size_t)tok_r[i] * OD + o;
                out[off]          = xo[i] + 0.1f * accGV[i];
                out[OFF_VN + off] = accVN[i];
            }
        }
    }
}

extern "C" void kernel_launch(void* const* d_in, const int* in_sizes, int n_in,
                              void* d_out, int out_size, void* d_ws, size_t ws_size,
                              hipStream_t stream)
{
    (void)in_sizes; (void)n_in; (void)out_size;
    const float* h  = (const float*)d_in[0];
    const float* x  = (const float*)d_in[1];
    const float* v  = (const float*)d_in[2];
    const float* rw = (const float*)d_in[3];
    const float* rb = (const float*)d_in[4];
    const float* mu = (const float*)d_in[5];
    const float* W1 = (const float*)d_in[6];
    const float* b1 = (const float*)d_in[7];
    const float* W2 = (const float*)d_in[8];
    const float* b2 = (const float*)d_in[9];
    float* out = (float*)d_out;

    char* ws = (char*)d_ws;
    int*    pcnt  = (int*)(ws + WS_PCNT);
    int*    total = (int*)(ws + WS_TOTAL);
    int*    table = (int*)(ws + WS_TABLE);
    int*    plist = (int*)(ws + WS_PLIST);
    float2* pwts  = (float2*)(ws + WS_PWTS);
    unsigned short* W1p  = (unsigned short*)(ws + WS_W1P);
    unsigned short* W2p  = (unsigned short*)(ws + WS_W2P);
    unsigned short* ctxb = (unsigned short*)(ws + WS_CTXB);

    bool preconv = (ws_size >= WS_NEED2);

    hipMemsetAsync(pcnt, 0, 64 * sizeof(int), stream);

    int pre_grid = preconv ? (3840 + NTOK) : 3840;
    pre_kernel<<<pre_grid, 256, 0, stream>>>(h, x, v, rw, rb, W1, W2,
                                             W1p, W2p, ctxb, out,
                                             pcnt, plist, pwts);
    prefix_kernel<<<1, 64, 0, stream>>>(pcnt, table, total);

    if (preconv) {
        moe_t<true><<<576, 512, 0, stream>>>(h, x, v, mu, b1, b2, W1p, W2p, ctxb,
                                             pcnt, table, total, plist, pwts, out);
    } else {
        moe_t<false><<<576, 512, 0, stream>>>(h, x, v, mu, b1, b2, W1p, W2p, ctxb,
                                              pcnt, table, total, plist, pwts, out);
    }
}